// Round 1
// 423.089 us; speedup vs baseline: 1.0055x; 1.0055x over previous
//
#include <hip/hip_runtime.h>
#include <hip/hip_bf16.h>
#include <cstdint>
#include <cstddef>

typedef unsigned short u16;
typedef __attribute__((ext_vector_type(8))) short short8;   // 8 bf16 = 4 VGPRs (MFMA A/B frag)
typedef __attribute__((ext_vector_type(4))) float f32x4;    // MFMA C/D frag

__device__ __forceinline__ u16 f2bf(float f) {
    union { float f; uint32_t u; } v; v.f = f;
    uint32_t u = v.u;
    return (u16)((u + 0x7fffu + ((u >> 16) & 1u)) >> 16);   // RNE
}
__device__ __forceinline__ float bf2f(u16 u) {
    union { uint32_t u; float f; } v; v.u = ((uint32_t)u) << 16;
    return v.f;
}

// async global->LDS 16B copy (m97: global_load_lds_dwordx4).
// LDS dest is wave-uniform base + lane*16; global addr is per-lane.
__device__ __forceinline__ void async_cp16(const u16* g, u16* l) {
    __builtin_amdgcn_global_load_lds(
        (const __attribute__((address_space(1))) unsigned int*)g,
        (__attribute__((address_space(3))) unsigned int*)l, 16, 0, 0);
}

// ---------------- cast fp32 -> bf16 (vectorized) ----------------
__global__ __launch_bounds__(256) void cast_f32_bf16(const float* __restrict__ in,
                                                     u16* __restrict__ out, int n) {
    int i = (blockIdx.x * 256 + threadIdx.x) * 4;
    if (i >= n) return;
    float4 v = *(const float4*)(in + i);
    ushort4 r;
    r.x = f2bf(v.x); r.y = f2bf(v.y); r.z = f2bf(v.z); r.w = f2bf(v.w);
    *(ushort4*)(out + i) = r;
}

// ---------------- W (K,N) fp32 -> Wt (N,K) bf16 (optionally pre-scaled) ----------------
__global__ __launch_bounds__(256) void transpose_cast(const float* __restrict__ W,
                                                      u16* __restrict__ Wt, int K, int N,
                                                      float smul) {
    __shared__ u16 tile[64][72];
    int kt = blockIdx.x * 64, nt = blockIdx.y * 64;
    int t = threadIdx.x;
#pragma unroll
    for (int i = 0; i < 16; i++) {
        int idx = t + i * 256; int kl = idx >> 6, nl = idx & 63;
        tile[kl][nl] = f2bf(W[(size_t)(kt + kl) * N + nt + nl] * smul);
    }
    __syncthreads();
#pragma unroll
    for (int i = 0; i < 16; i++) {
        int idx = t + i * 256; int nl = idx >> 6, kl = idx & 63;
        Wt[(size_t)(nt + nl) * K + kt + kl] = tile[kl][nl];
    }
}

// ---------------- bf16 GEMM (m97 structure), compile-time shapes ----------------
// C(M,NDIM) = A(M,KDIM rows of lda) @ Bt(NDIM,KDIM)^T ; C row stride = ldc.
// 128x128 tile, BK=32, 4 waves 2x2, mfma 16x16x32, async global_load_lds staging.
template <int OUTF32, int KDIM, int NDIM>
__global__ __launch_bounds__(256) void gemm_bt(const u16* __restrict__ A, int lda,
                                               const u16* __restrict__ Bt,
                                               void* __restrict__ Cout, int ldc) {
    __shared__ __align__(16) u16 Al[128 * 32];   // 8 KB, rows of 32 elems (64 B), no pad
    __shared__ __align__(16) u16 Bl[128 * 32];
    int m0 = blockIdx.x * 128, n0 = blockIdx.y * 128;
    int t = threadIdx.x;
    int w = t >> 6, l = t & 63;
    int lm = l & 15, lq = l >> 4;
    int wm = (w >> 1) * 64, wn = (w & 1) * 64;
    f32x4 acc[4][4] = {};

    for (int k0 = 0; k0 < KDIM; k0 += 32) {
#pragma unroll
        for (int c = 0; c < 2; c++) {
            int chunk = w * 128 + c * 64 + l;          // per-lane chunk id
            int row = chunk >> 2, col8 = (chunk & 3) * 8;
            async_cp16(A + (size_t)(m0 + row) * lda + k0 + col8,
                       Al + (w * 128 + c * 64) * 8);   // wave-uniform LDS base
            int brow = n0 + row;
            if (NDIM % 128 != 0) { if (brow >= NDIM) brow = NDIM - 1; }  // partial-N clamp
            async_cp16(Bt + (size_t)brow * KDIM + k0 + col8,
                       Bl + (w * 128 + c * 64) * 8);
        }
        __syncthreads();
        short8 af[4], bfr[4];
#pragma unroll
        for (int mt = 0; mt < 4; mt++)
            af[mt] = *(const short8*)(Al + (wm + mt * 16 + lm) * 32 + lq * 8);
#pragma unroll
        for (int nt = 0; nt < 4; nt++)
            bfr[nt] = *(const short8*)(Bl + (wn + nt * 16 + lm) * 32 + lq * 8);
#pragma unroll
        for (int mt = 0; mt < 4; mt++)
#pragma unroll
            for (int nt = 0; nt < 4; nt++)
                acc[mt][nt] = __builtin_amdgcn_mfma_f32_16x16x32_bf16(af[mt], bfr[nt], acc[mt][nt], 0, 0, 0);
        __syncthreads();
    }
#pragma unroll
    for (int mt = 0; mt < 4; mt++) {
#pragma unroll
        for (int nt = 0; nt < 4; nt++) {
            int col = n0 + wn + nt * 16 + lm;
            if (col < NDIM) {
#pragma unroll
                for (int r = 0; r < 4; r++) {
                    int row = m0 + wm + mt * 16 + lq * 4 + r;
                    if (OUTF32) ((float*)Cout)[(size_t)row * ldc + col] = acc[mt][nt][r];
                    else        ((u16*)Cout)[(size_t)row * ldc + col] = f2bf(acc[mt][nt][r]);
                }
            }
        }
    }
}

// ---------------- RoPE in-place on (rows, nheads*64) bf16, row stride `stride` ----------------
__global__ __launch_bounds__(256) void rope_kernel(u16* __restrict__ x, int rows,
                                                   int nheads, int Smask, int stride) {
    int i = blockIdx.x * 256 + threadIdx.x;
    int total = rows * nheads * 32;
    if (i >= total) return;
    int j = i & 31;
    int h = (i >> 5) % nheads;
    int row = i / (32 * nheads);
    int pos = row & Smask;                       // pos = s (S power of two)
    float f = exp2f((float)j * -0.4152410118609828f);
    float ang = (float)pos * f;
    float c = cosf(ang), s = sinf(ang);
    u16* p = x + (size_t)row * stride + h * 64 + j;
    float x1 = bf2f(p[0]), x2 = bf2f(p[32]);
    p[0]  = f2bf(x1 * c - x2 * s);
    p[32] = f2bf(x2 * c + x1 * s);
}

// ---------------- V slice of kv -> v_t (B,H,128,S) bf16 ----------------
__global__ __launch_bounds__(256) void transpose_v(const u16* __restrict__ kv,
                                                   u16* __restrict__ vt, int S) {
    __shared__ u16 tile[64][72];
    int bh = blockIdx.z; int b = bh >> 4, h = bh & 15;
    int s0 = blockIdx.x * 64, d0 = blockIdx.y * 64;
    int t = threadIdx.x;
#pragma unroll
    for (int i = 0; i < 16; i++) {
        int idx = t + i * 256; int sl = idx >> 6, dl = idx & 63;
        tile[sl][dl] = kv[(size_t)(b * S + s0 + sl) * 4096 + 2048 + h * 128 + d0 + dl];
    }
    __syncthreads();
#pragma unroll
    for (int i = 0; i < 16; i++) {
        int idx = t + i * 256; int dl = idx >> 6, sl = idx & 63;
        vt[((size_t)(bh * 128 + d0 + dl)) * S + s0 + sl] = tile[sl][dl];
    }
}

// ---------------- Flash MLA attention v5 ----------------
// Changes vs v4:
//  * one q-tile per block: grid (bh=32, y=32), qt = 31 - y (heavy blocks dispatch
//    first -> LPT scheduling; 1024 blocks -> 3 blocks/CU resident (LDS 52KB limit)
//    instead of 2 -> latency hiding across blocks at every barrier).
//    Linear id = bh + 32*y keeps XCD = bh%8 pinning (same L2 locality as v4).
//  * softmax in exp2 domain: log2(e) folded into Q pre-scale (saves a v_mul per exp).
//  * defer-max (T13, THR=8): skip O/l rescale when tile max grew <= 8 in log2
//    domain (P bounded by 2^8 -> fine in bf16/f32). Skips ~every tile here.
//  * s_setprio(1) around MFMA clusters (T5).
// S^T = K·Q^T -> C: col=q, row=key. Each lane owns ONE q-row (2-shfl softmax).
// O^T = V^T·P^T -> C: col=q, row=dim; packed 8B stores.
__global__ __launch_bounds__(256) void mla_attn(const u16* __restrict__ qc, int qcs,
                                                const u16* __restrict__ qr, int qrs,
                                                const u16* __restrict__ kvbuf,
                                                const u16* __restrict__ kr, int krs,
                                                const u16* __restrict__ vt,
                                                u16* __restrict__ out, int S) {
    __shared__ __align__(16) u16 Kl[64 * 200];       // 64 keys x 192 dims, stride 200
    __shared__ __align__(16) u16 Vl[128 * 72];       // 128 dims x 64 keys, stride 72
    __shared__ __align__(16) u16 Plds[4][16 * 72];   // per-wave P[q][key], stride 72
    int bh = blockIdx.x; int b = bh >> 4, h = bh & 15;   // XCD-pinning: XCD = bh%8
    int qt = 31 - (int)blockIdx.y;                   // heavy-first (LPT)
    int t = threadIdx.x, w = t >> 6, l = t & 63;
    int lm = l & 15, lq = l >> 4;

    short8 kreg[6], vreg[4];
    auto load_tile = [&](int kbase) {
#pragma unroll
        for (int c = 0; c < 6; c++) {                 // K: 64 rows x 24 chunks(16B)
            int idx = t + c * 256;
            int row = idx / 24, col = (idx % 24) * 8;
            const u16* src = (col < 128)
                ? kvbuf + (size_t)(b * S + kbase + row) * 4096 + h * 128 + col
                : kr + (size_t)(b * S + kbase + row) * krs + (col - 128);
            kreg[c] = *(const short8*)src;
        }
#pragma unroll
        for (int c = 0; c < 4; c++) {                 // V^T: 128 rows x 8 chunks(16B)
            int idx = t + c * 256;
            int row = idx >> 3, col = (idx & 7) * 8;
            vreg[c] = *(const short8*)(vt + ((size_t)bh * 128 + row) * S + kbase + col);
        }
    };

    int qrow = qt * 64 + w * 16;                      // this wave's 16 q-rows
    int ntiles = qt + 1;

    // Q B-frags: B[n=q=lane&15][k=lq*8+j] (pre-scaled by 1/sqrt(192)*log2e)
    short8 bq[6];
    {
        const u16* qc_row = qc + (size_t)(b * S + qrow + lm) * qcs + h * 128;
#pragma unroll
        for (int ks = 0; ks < 4; ks++) bq[ks] = *(const short8*)(qc_row + ks * 32 + lq * 8);
        const u16* qr_row = qr + (size_t)(b * S + qrow + lm) * qrs + h * 64;
#pragma unroll
        for (int ks = 0; ks < 2; ks++) bq[4 + ks] = *(const short8*)(qr_row + ks * 32 + lq * 8);
    }

    f32x4 o[8] = {};                              // O^T accs: 8 dim-tiles x (4 rows)
    float m_s = -INFINITY, l_s = 0.f;             // per-lane state for q-row (qrow+lm)

    load_tile(0);
    for (int kt = 0; kt < ntiles; kt++) {
        int kbase = kt * 64;
        __syncthreads();                          // prior iter's LDS reads done
#pragma unroll
        for (int c = 0; c < 6; c++) {
            int idx = t + c * 256;
            int row = idx / 24, col = (idx % 24) * 8;
            *(short8*)(Kl + row * 200 + col) = kreg[c];
        }
#pragma unroll
        for (int c = 0; c < 4; c++) {
            int idx = t + c * 256;
            int row = idx >> 3, col = (idx & 7) * 8;
            *(short8*)(Vl + row * 72 + col) = vreg[c];
        }
        __syncthreads();                          // staging visible to all waves
        if (kt + 1 < ntiles) load_tile(kbase + 64);   // overlaps compute below

        if (kbase > qrow + 15) continue;          // fully-masked for this wave

        // S^T: acc[mt][r] = S_log2[q=qrow+lm][key=kbase+mt*16+lq*4+r]
        f32x4 acc[4] = {};
        __builtin_amdgcn_s_setprio(1);
#pragma unroll
        for (int ks = 0; ks < 6; ks++) {
#pragma unroll
            for (int mt = 0; mt < 4; mt++) {
                short8 ak = *(const short8*)(Kl + (mt * 16 + lm) * 200 + ks * 32 + lq * 8);
                acc[mt] = __builtin_amdgcn_mfma_f32_16x16x32_bf16(ak, bq[ks], acc[mt], 0, 0, 0);
            }
        }
        __builtin_amdgcn_s_setprio(0);
        if (kbase + 63 > qrow) {                  // diagonal tile: causal mask
            int qi = qrow + lm;
#pragma unroll
            for (int mt = 0; mt < 4; mt++)
#pragma unroll
                for (int r = 0; r < 4; r++) {
                    int ki = kbase + mt * 16 + lq * 4 + r;
                    if (ki > qi) acc[mt][r] = -INFINITY;
                }
        }
        // online softmax (log2 domain): intra-lane over 16 regs, then xor16/xor32
        float mx = -INFINITY;
#pragma unroll
        for (int mt = 0; mt < 4; mt++)
#pragma unroll
            for (int r = 0; r < 4; r++) mx = fmaxf(mx, acc[mt][r]);
        mx = fmaxf(mx, __shfl_xor(mx, 16));
        mx = fmaxf(mx, __shfl_xor(mx, 32));
        // defer-max: only rescale if some row's max grew by > 8 (P <= 2^8 otherwise)
        if (!__all(mx - m_s <= 8.0f)) {
            float mnew = fmaxf(m_s, mx);
            float alpha = exp2f(m_s - mnew);
            m_s = mnew;
            l_s *= alpha;
#pragma unroll
            for (int mt = 0; mt < 8; mt++)
#pragma unroll
                for (int r = 0; r < 4; r++) o[mt][r] *= alpha;
        }

        u16* pl = Plds[w];
        float rs = 0.f;
#pragma unroll
        for (int mt = 0; mt < 4; mt++) {
            float p0 = exp2f(acc[mt][0] - m_s);
            float p1 = exp2f(acc[mt][1] - m_s);
            float p2 = exp2f(acc[mt][2] - m_s);
            float p3 = exp2f(acc[mt][3] - m_s);
            rs += (p0 + p1) + (p2 + p3);
            ushort4 pk; pk.x = f2bf(p0); pk.y = f2bf(p1); pk.z = f2bf(p2); pk.w = f2bf(p3);
            *(ushort4*)(pl + lm * 72 + mt * 16 + lq * 4) = pk;   // ds_write_b64
        }
        rs += __shfl_xor(rs, 16);
        rs += __shfl_xor(rs, 32);
        l_s += rs;

        // O^T += V^T · P^T : A=V^T[m=dim][k=key], B=P[n=q][k=key]
        __builtin_amdgcn_s_setprio(1);
#pragma unroll
        for (int ks2 = 0; ks2 < 2; ks2++) {
            short8 bp = *(const short8*)(pl + lm * 72 + ks2 * 32 + lq * 8);
#pragma unroll
            for (int mt = 0; mt < 8; mt++) {
                short8 av = *(const short8*)(Vl + (mt * 16 + lm) * 72 + ks2 * 32 + lq * 8);
                o[mt] = __builtin_amdgcn_mfma_f32_16x16x32_bf16(av, bp, o[mt], 0, 0, 0);
            }
        }
        __builtin_amdgcn_s_setprio(0);
    }
    // epilogue: O^T C-layout: col=q=lm, row=dim=mt*16+lq*4+r -> packed 8B stores
    float inv = 1.0f / l_s;
    u16* orow = out + (size_t)(b * S + qrow + lm) * 2048 + h * 128;
#pragma unroll
    for (int mt = 0; mt < 8; mt++) {
        ushort4 pk;
        pk.x = f2bf(o[mt][0] * inv);
        pk.y = f2bf(o[mt][1] * inv);
        pk.z = f2bf(o[mt][2] * inv);
        pk.w = f2bf(o[mt][3] * inv);
        *(ushort4*)(orow + mt * 16 + lq * 4) = pk;
    }
}

extern "C" void kernel_launch(void* const* d_in, const int* in_sizes, int n_in,
                              void* d_out, int out_size, void* d_ws, size_t ws_size,
                              hipStream_t stream) {
    const int B = 2, S = 2048, D = 2048, H = 16;
    const int M = B * S;                       // 4096
    const int NP = 3648;                       // merged proj cols: 2048+1024+512+64
    const int NPpad = 3712;                    // 29 tiles of 128
    // 1/sqrt(192) * log2(e): softmax runs in exp2 domain (folded into Wq/Wq_rope)
    const float scale = 0.07216878364870323f * 1.4426950408889634f;
    const float* x    = (const float*)d_in[0];
    const float* Wq   = (const float*)d_in[1];
    const float* Wqr  = (const float*)d_in[2];
    const float* Wkvd = (const float*)d_in[3];
    const float* Wkvu = (const float*)d_in[4];
    const float* Wkr  = (const float*)d_in[5];
    const float* Wo   = (const float*)d_in[6];

    u16* p = (u16*)d_ws;
    u16* xb     = p; p += (size_t)M * D;             // 16.8 MB
    u16* WprojT = p; p += (size_t)NPpad * 2048;      // rows: [Wq|Wqr|Wkvd|Wkr|pad]
    u16* WkvuT  = p; p += (size_t)4096 * 512;
    u16* WoT    = p; p += (size_t)2048 * 2048;
    u16* proj   = p; p += (size_t)M * NPpad;         // [q_c|q_r|c_kv|k_r] row-major
    u16* kv     = p; p += (size_t)M * 4096;
    u16* v_t    = p; p += (size_t)B * H * 128 * S;
    u16* attn   = p; p += (size_t)M * 2048;

    u16* q_c = proj;                 // cols 0..2047
    u16* q_r = proj + 2048;          // cols 2048..3071
    u16* ckv = proj + 3072;          // cols 3072..3583
    u16* k_r = proj + 3584;          // cols 3584..3647

    // 1) casts / transposes (Wq, Wq_rope pre-scaled by 1/sqrt(192)*log2e)
    cast_f32_bf16<<<(M * D) / 4 / 256, 256, 0, stream>>>(x, xb, M * D);
    transpose_cast<<<dim3(32, 32), 256, 0, stream>>>(Wq,   WprojT,               2048, 2048, scale);
    transpose_cast<<<dim3(32, 16), 256, 0, stream>>>(Wqr,  WprojT + 2048 * 2048, 2048, 1024, scale);
    transpose_cast<<<dim3(32, 8),  256, 0, stream>>>(Wkvd, WprojT + 3072 * 2048, 2048, 512, 1.0f);
    transpose_cast<<<dim3(32, 1),  256, 0, stream>>>(Wkr,  WprojT + 3584 * 2048, 2048, 64, 1.0f);
    transpose_cast<<<dim3(8, 64),  256, 0, stream>>>(Wkvu, WkvuT, 512, 4096, 1.0f);
    transpose_cast<<<dim3(32, 32), 256, 0, stream>>>(Wo,   WoT,   2048, 2048, 1.0f);

    // 2) merged projection GEMM: proj = xb @ WprojT^T  (grid 32x29 = 928 blocks)
    gemm_bt<0, 2048, NP><<<dim3(32, 29), 256, 0, stream>>>(xb, 2048, WprojT, proj, NPpad);

    // 3) RoPE (in place on proj slices; q_r pre-scaled — rotation linear, scale commutes)
    rope_kernel<<<(M * 16 * 32) / 256, 256, 0, stream>>>(q_r, M, 16, S - 1, NPpad);
    rope_kernel<<<(M * 32) / 256, 256, 0, stream>>>(k_r, M, 1, S - 1, NPpad);

    // 4) kv up-projection (A = c_kv inside proj, lda = NPpad), V transpose
    gemm_bt<0, 512, 4096><<<dim3(32, 32), 256, 0, stream>>>(ckv, NPpad, WkvuT, kv, 4096);
    transpose_v<<<dim3(32, 2, 32), 256, 0, stream>>>(kv, v_t, S);

    // 5) attention — grid (bh, 32 q-tiles): one q-tile/block, heavy-first, XCD-pinned
    mla_attn<<<dim3(32, 32), 256, 0, stream>>>(q_c, NPpad, q_r, NPpad, kv, k_r, NPpad,
                                               v_t, attn, S);

    // 6) output projection -> fp32 d_out
    gemm_bt<1, 2048, 2048><<<dim3(32, 16), 256, 0, stream>>>(attn, 2048, WoT, d_out, 2048);
}

// Round 3
// 418.554 us; speedup vs baseline: 1.0164x; 1.0108x over previous
//
#include <hip/hip_runtime.h>
#include <hip/hip_bf16.h>
#include <cstdint>
#include <cstddef>

typedef unsigned short u16;
typedef __attribute__((ext_vector_type(8))) short short8;   // 8 bf16 = 4 VGPRs (MFMA A/B frag)
typedef __attribute__((ext_vector_type(4))) float f32x4;    // MFMA C/D frag (16x16)
typedef __attribute__((ext_vector_type(16))) float f32x16;  // MFMA C/D frag (32x32)

__device__ __forceinline__ u16 f2bf(float f) {
    union { float f; uint32_t u; } v; v.f = f;
    uint32_t u = v.u;
    return (u16)((u + 0x7fffu + ((u >> 16) & 1u)) >> 16);   // RNE
}
__device__ __forceinline__ float bf2f(u16 u) {
    union { uint32_t u; float f; } v; v.u = ((uint32_t)u) << 16;
    return v.f;
}
// pack two f32 -> one dword of 2 bf16 (lo|hi<<16), pure bit-ops
__device__ __forceinline__ uint32_t pk2(float lo, float hi) {
    return (uint32_t)f2bf(lo) | ((uint32_t)f2bf(hi) << 16);
}

// async global->LDS 16B copy (m97: global_load_lds_dwordx4).
__device__ __forceinline__ void async_cp16(const u16* g, u16* l) {
    __builtin_amdgcn_global_load_lds(
        (const __attribute__((address_space(1))) unsigned int*)g,
        (__attribute__((address_space(3))) unsigned int*)l, 16, 0, 0);
}

// ---------------- cast fp32 -> bf16 (vectorized) ----------------
__global__ __launch_bounds__(256) void cast_f32_bf16(const float* __restrict__ in,
                                                     u16* __restrict__ out, int n) {
    int i = (blockIdx.x * 256 + threadIdx.x) * 4;
    if (i >= n) return;
    float4 v = *(const float4*)(in + i);
    ushort4 r;
    r.x = f2bf(v.x); r.y = f2bf(v.y); r.z = f2bf(v.z); r.w = f2bf(v.w);
    *(ushort4*)(out + i) = r;
}

// ---------------- W (K,N) fp32 -> Wt (N,K) bf16 (optionally pre-scaled) ----------------
__global__ __launch_bounds__(256) void transpose_cast(const float* __restrict__ W,
                                                      u16* __restrict__ Wt, int K, int N,
                                                      float smul) {
    __shared__ u16 tile[64][72];
    int kt = blockIdx.x * 64, nt = blockIdx.y * 64;
    int t = threadIdx.x;
#pragma unroll
    for (int i = 0; i < 16; i++) {
        int idx = t + i * 256; int kl = idx >> 6, nl = idx & 63;
        tile[kl][nl] = f2bf(W[(size_t)(kt + kl) * N + nt + nl] * smul);
    }
    __syncthreads();
#pragma unroll
    for (int i = 0; i < 16; i++) {
        int idx = t + i * 256; int nl = idx >> 6, kl = idx & 63;
        Wt[(size_t)(nt + nl) * K + kt + kl] = tile[kl][nl];
    }
}

// ---------------- bf16 GEMM (m97 structure), compile-time shapes ----------------
template <int OUTF32, int KDIM, int NDIM>
__global__ __launch_bounds__(256) void gemm_bt(const u16* __restrict__ A, int lda,
                                               const u16* __restrict__ Bt,
                                               void* __restrict__ Cout, int ldc) {
    __shared__ __align__(16) u16 Al[128 * 32];
    __shared__ __align__(16) u16 Bl[128 * 32];
    int m0 = blockIdx.x * 128, n0 = blockIdx.y * 128;
    int t = threadIdx.x;
    int w = t >> 6, l = t & 63;
    int lm = l & 15, lq = l >> 4;
    int wm = (w >> 1) * 64, wn = (w & 1) * 64;
    f32x4 acc[4][4] = {};

    for (int k0 = 0; k0 < KDIM; k0 += 32) {
#pragma unroll
        for (int c = 0; c < 2; c++) {
            int chunk = w * 128 + c * 64 + l;
            int row = chunk >> 2, col8 = (chunk & 3) * 8;
            async_cp16(A + (size_t)(m0 + row) * lda + k0 + col8,
                       Al + (w * 128 + c * 64) * 8);
            int brow = n0 + row;
            if (NDIM % 128 != 0) { if (brow >= NDIM) brow = NDIM - 1; }
            async_cp16(Bt + (size_t)brow * KDIM + k0 + col8,
                       Bl + (w * 128 + c * 64) * 8);
        }
        __syncthreads();
        short8 af[4], bfr[4];
#pragma unroll
        for (int mt = 0; mt < 4; mt++)
            af[mt] = *(const short8*)(Al + (wm + mt * 16 + lm) * 32 + lq * 8);
#pragma unroll
        for (int nt = 0; nt < 4; nt++)
            bfr[nt] = *(const short8*)(Bl + (wn + nt * 16 + lm) * 32 + lq * 8);
#pragma unroll
        for (int mt = 0; mt < 4; mt++)
#pragma unroll
            for (int nt = 0; nt < 4; nt++)
                acc[mt][nt] = __builtin_amdgcn_mfma_f32_16x16x32_bf16(af[mt], bfr[nt], acc[mt][nt], 0, 0, 0);
        __syncthreads();
    }
#pragma unroll
    for (int mt = 0; mt < 4; mt++) {
#pragma unroll
        for (int nt = 0; nt < 4; nt++) {
            int col = n0 + wn + nt * 16 + lm;
            if (col < NDIM) {
#pragma unroll
                for (int r = 0; r < 4; r++) {
                    int row = m0 + wm + mt * 16 + lq * 4 + r;
                    if (OUTF32) ((float*)Cout)[(size_t)row * ldc + col] = acc[mt][nt][r];
                    else        ((u16*)Cout)[(size_t)row * ldc + col] = f2bf(acc[mt][nt][r]);
                }
            }
        }
    }
}

// ---------------- RoPE in-place on (rows, nheads*64) bf16, row stride `stride` ----------------
__global__ __launch_bounds__(256) void rope_kernel(u16* __restrict__ x, int rows,
                                                   int nheads, int Smask, int stride) {
    int i = blockIdx.x * 256 + threadIdx.x;
    int total = rows * nheads * 32;
    if (i >= total) return;
    int j = i & 31;
    int h = (i >> 5) % nheads;
    int row = i / (32 * nheads);
    int pos = row & Smask;
    float f = exp2f((float)j * -0.4152410118609828f);
    float ang = (float)pos * f;
    float c = cosf(ang), s = sinf(ang);
    u16* p = x + (size_t)row * stride + h * 64 + j;
    float x1 = bf2f(p[0]), x2 = bf2f(p[32]);
    p[0]  = f2bf(x1 * c - x2 * s);
    p[32] = f2bf(x2 * c + x1 * s);
}

// ---------------- V slice of kv -> v_t (B,H,128,S) bf16 ----------------
__global__ __launch_bounds__(256) void transpose_v(const u16* __restrict__ kv,
                                                   u16* __restrict__ vt, int S) {
    __shared__ u16 tile[64][72];
    int bh = blockIdx.z; int b = bh >> 4, h = bh & 15;
    int s0 = blockIdx.x * 64, d0 = blockIdx.y * 64;
    int t = threadIdx.x;
#pragma unroll
    for (int i = 0; i < 16; i++) {
        int idx = t + i * 256; int sl = idx >> 6, dl = idx & 63;
        tile[sl][dl] = kv[(size_t)(b * S + s0 + sl) * 4096 + 2048 + h * 128 + d0 + dl];
    }
    __syncthreads();
#pragma unroll
    for (int i = 0; i < 16; i++) {
        int idx = t + i * 256; int dl = idx >> 6, sl = idx & 63;
        vt[((size_t)(bh * 128 + d0 + dl)) * S + s0 + sl] = tile[sl][dl];
    }
}

// ---------------- Flash MLA attention v7: 32x32 MFMA, de-risked ----------------
// v6 post-mortem: NaN. Structural trap: -INF mask value + any C-layout slip ->
// fully-masked lane -> mx=-INF -> (mx-m_s)=NaN in defer check -> alpha=NaN.
// v7 changes vs v6:
//  * NaN-proof softmax: mask = -1e30f (finite), m_s init = 0.0f. Online softmax vs
//    reference max 0 is exact (defer-max keeps P <= 2^8); NO infinities anywhere, so
//    any layout error -> finite wrong answer, never NaN.
//  * all exotic asm removed: exp2f() (proven), P pack via f2bf bit-ops (proven),
//    cross-half exchange via __shfl_xor(.,32) (proven) + select. 16 ds_bpermute/tile
//    still ~10x less DS than v5's P LDS round-trip.
// Structure (kept from v6): mfma_f32_32x32x16_bf16, 32 q-rows/wave, K/V LDS reads
// amortized 2x, P stays in registers. grid (32,16), qt = y<8?15-y:y-8 (co-resident
// pair same bh -> K/V L2 reuse, uniform work).
__global__ __launch_bounds__(256, 2) void mla_attn(const u16* __restrict__ qc, int qcs,
                                                   const u16* __restrict__ qr, int qrs,
                                                   const u16* __restrict__ kvbuf,
                                                   const u16* __restrict__ kr, int krs,
                                                   const u16* __restrict__ vt,
                                                   u16* __restrict__ out, int S) {
    __shared__ __align__(16) u16 Kl[64 * 200];       // 64 keys x 192 dims, stride 200
    __shared__ __align__(16) u16 Vl[128 * 72];       // 128 dims x 64 keys, stride 72
    const float NEG = -1e30f;
    int bh = blockIdx.x; int b = bh >> 4, h = bh & 15;   // XCD-pinning: XCD = bh%8
    int y = blockIdx.y;
    int qt = (y < 8) ? (15 - y) : (y - 8);
    int t = threadIdx.x, w = t >> 6, l = t & 63;
    int ln = l & 31, hi = l >> 5;

    short8 kreg[6], vreg[4];
    auto load_tile = [&](int kbase) {
#pragma unroll
        for (int c = 0; c < 6; c++) {                 // K: 64 rows x 24 chunks(16B)
            int idx = t + c * 256;
            int row = idx / 24, col = (idx % 24) * 8;
            const u16* src = (col < 128)
                ? kvbuf + (size_t)(b * S + kbase + row) * 4096 + h * 128 + col
                : kr + (size_t)(b * S + kbase + row) * krs + (col - 128);
            kreg[c] = *(const short8*)src;
        }
#pragma unroll
        for (int c = 0; c < 4; c++) {                 // V^T: 128 rows x 8 chunks(16B)
            int idx = t + c * 256;
            int row = idx >> 3, col = (idx & 7) * 8;
            vreg[c] = *(const short8*)(vt + ((size_t)bh * 128 + row) * S + kbase + col);
        }
    };

    int qrow = qt * 128 + w * 32;                     // this wave's 32 q-rows
    int ntiles = 2 * qt + 2;

    // Q B-frags for 32x32x16: lane holds col q=ln, k = ks*16 + hi*8 + j (pre-scaled)
    short8 bq[12];
    {
        const u16* qc_row = qc + (size_t)(b * S + qrow + ln) * qcs + h * 128;
#pragma unroll
        for (int ks = 0; ks < 8; ks++) bq[ks] = *(const short8*)(qc_row + ks * 16 + hi * 8);
        const u16* qr_row = qr + (size_t)(b * S + qrow + ln) * qrs + h * 64;
#pragma unroll
        for (int ks = 0; ks < 4; ks++) bq[8 + ks] = *(const short8*)(qr_row + ks * 16 + hi * 8);
    }

    f32x16 o[4] = {};                             // O^T: 4 dim-tiles x (32x32 C)
    float m_s = 0.0f, l_s = 0.f;                  // running max (ref 0) / denom

    load_tile(0);
    for (int kt = 0; kt < ntiles; kt++) {
        int kbase = kt * 64;
        __syncthreads();                          // prior iter's LDS reads done
#pragma unroll
        for (int c = 0; c < 6; c++) {
            int idx = t + c * 256;
            int row = idx / 24, col = (idx % 24) * 8;
            *(short8*)(Kl + row * 200 + col) = kreg[c];
        }
#pragma unroll
        for (int c = 0; c < 4; c++) {
            int idx = t + c * 256;
            int row = idx >> 3, col = (idx & 7) * 8;
            *(short8*)(Vl + row * 72 + col) = vreg[c];
        }
        __syncthreads();                          // staging visible to all waves
        if (kt + 1 < ntiles) load_tile(kbase + 64);   // overlaps compute below

        if (kbase > qrow + 31) continue;          // fully-masked for this wave

        // S^T tiles: sacc[kt2][r] = S_log2[key=kbase+kt2*32+(r&3)+8(r>>2)+4hi][q=qrow+ln]
        f32x16 sacc[2] = {};
        __builtin_amdgcn_s_setprio(1);
#pragma unroll
        for (int ks = 0; ks < 12; ks++) {
            short8 ak0 = *(const short8*)(Kl + ln * 200 + ks * 16 + hi * 8);
            short8 ak1 = *(const short8*)(Kl + (32 + ln) * 200 + ks * 16 + hi * 8);
            sacc[0] = __builtin_amdgcn_mfma_f32_32x32x16_bf16(ak0, bq[ks], sacc[0], 0, 0, 0);
            sacc[1] = __builtin_amdgcn_mfma_f32_32x32x16_bf16(ak1, bq[ks], sacc[1], 0, 0, 0);
        }
        __builtin_amdgcn_s_setprio(0);

        if (kbase + 63 > qrow) {                  // diagonal tiles: causal mask (finite)
            int qi = qrow + ln;
#pragma unroll
            for (int kt2 = 0; kt2 < 2; kt2++)
#pragma unroll
                for (int r = 0; r < 16; r++) {
                    int key = kbase + kt2 * 32 + (r & 3) + 8 * (r >> 2) + 4 * hi;
                    if (key > qi) sacc[kt2][r] = NEG;
                }
        }

        // online softmax (log2 domain, ref max 0), lane pair (l, l^32) shares q-row
        float mx = NEG;
#pragma unroll
        for (int kt2 = 0; kt2 < 2; kt2++)
#pragma unroll
            for (int r = 0; r < 16; r++) mx = fmaxf(mx, sacc[kt2][r]);
        mx = fmaxf(mx, __shfl_xor(mx, 32));
        if (!__all(mx - m_s <= 8.0f)) {           // defer-max (T13): P <= 2^8 otherwise
            float mnew = fmaxf(m_s, mx);
            float alpha = exp2f(m_s - mnew);
            m_s = mnew;
            l_s *= alpha;
#pragma unroll
            for (int dt = 0; dt < 4; dt++) o[dt] *= alpha;
        }

        // P = 2^(S-m): exp + pack to bf16 B-frags in-register; cross-half via shfl_xor
        float rs = 0.f;
        short8 bp[2][2];
#pragma unroll
        for (int kt2 = 0; kt2 < 2; kt2++) {
            float p[16];
#pragma unroll
            for (int r = 0; r < 16; r++) p[r] = exp2f(sacc[kt2][r] - m_s);
#pragma unroll
            for (int r = 0; r < 16; r++) rs += p[r];
            // keys (rel to kt2*32): own regs hold 4hi+{0..3}, 8+4hi+{0..3}, 16+.., 24+..
            uint32_t c0 = pk2(p[0], p[1]),  c1 = pk2(p[2], p[3]);    // keys 4hi+0..3
            uint32_t c2 = pk2(p[4], p[5]),  c3 = pk2(p[6], p[7]);    // keys 8+4hi+0..3
            uint32_t e0 = __shfl_xor(c0, 32), e1 = __shfl_xor(c1, 32);
            uint32_t e2 = __shfl_xor(c2, 32), e3 = __shfl_xor(c3, 32);
            // B-frag s=0 wants keys 8hi+0..7 per lane:
            union { uint32_t u[4]; short8 s; } f0;
            f0.u[0] = hi ? e2 : c0;   // (8,9)   | (0,1)
            f0.u[1] = hi ? e3 : c1;   // (10,11) | (2,3)
            f0.u[2] = hi ? c2 : e0;   // (12,13) | (4,5)
            f0.u[3] = hi ? c3 : e1;   // (14,15) | (6,7)
            bp[kt2][0] = f0.s;
            uint32_t c4 = pk2(p[8], p[9]),   c5 = pk2(p[10], p[11]); // keys 16+4hi+0..3
            uint32_t c6 = pk2(p[12], p[13]), c7 = pk2(p[14], p[15]); // keys 24+4hi+0..3
            uint32_t e4 = __shfl_xor(c4, 32), e5 = __shfl_xor(c5, 32);
            uint32_t e6 = __shfl_xor(c6, 32), e7 = __shfl_xor(c7, 32);
            union { uint32_t u[4]; short8 s; } f1;
            f1.u[0] = hi ? e6 : c4;
            f1.u[1] = hi ? e7 : c5;
            f1.u[2] = hi ? c6 : e4;
            f1.u[3] = hi ? c7 : e5;
            bp[kt2][1] = f1.s;
        }
        rs += __shfl_xor(rs, 32);
        l_s += rs;

        // O^T += V^T · P : A=V^T[dim][key] from LDS, B=P[key][q] in regs
        __builtin_amdgcn_s_setprio(1);
#pragma unroll
        for (int kt2 = 0; kt2 < 2; kt2++)
#pragma unroll
            for (int s = 0; s < 2; s++)
#pragma unroll
                for (int dt = 0; dt < 4; dt++) {
                    short8 av = *(const short8*)(Vl + (dt * 32 + ln) * 72 + kt2 * 32 + s * 16 + hi * 8);
                    o[dt] = __builtin_amdgcn_mfma_f32_32x32x16_bf16(av, bp[kt2][s], o[dt], 0, 0, 0);
                }
        __builtin_amdgcn_s_setprio(0);
    }

    // epilogue: C col=q=ln, row=dim=dt*32+(r&3)+8*(r>>2)+4hi -> 4-consecutive-dim packs
    float inv = 1.0f / l_s;
    u16* orow = out + (size_t)(b * S + qrow + ln) * 2048 + h * 128;
#pragma unroll
    for (int dt = 0; dt < 4; dt++)
#pragma unroll
        for (int g = 0; g < 4; g++) {
            ushort4 pk4;
            pk4.x = f2bf(o[dt][g * 4 + 0] * inv);
            pk4.y = f2bf(o[dt][g * 4 + 1] * inv);
            pk4.z = f2bf(o[dt][g * 4 + 2] * inv);
            pk4.w = f2bf(o[dt][g * 4 + 3] * inv);
            *(ushort4*)(orow + dt * 32 + g * 8 + hi * 4) = pk4;
        }
}

extern "C" void kernel_launch(void* const* d_in, const int* in_sizes, int n_in,
                              void* d_out, int out_size, void* d_ws, size_t ws_size,
                              hipStream_t stream) {
    const int B = 2, S = 2048, D = 2048, H = 16;
    const int M = B * S;                       // 4096
    const int NP = 3648;                       // merged proj cols: 2048+1024+512+64
    const int NPpad = 3712;                    // 29 tiles of 128
    // 1/sqrt(192) * log2(e): softmax runs in exp2 domain (folded into Wq/Wq_rope)
    const float scale = 0.07216878364870323f * 1.4426950408889634f;
    const float* x    = (const float*)d_in[0];
    const float* Wq   = (const float*)d_in[1];
    const float* Wqr  = (const float*)d_in[2];
    const float* Wkvd = (const float*)d_in[3];
    const float* Wkvu = (const float*)d_in[4];
    const float* Wkr  = (const float*)d_in[5];
    const float* Wo   = (const float*)d_in[6];

    u16* p = (u16*)d_ws;
    u16* xb     = p; p += (size_t)M * D;             // 16.8 MB
    u16* WprojT = p; p += (size_t)NPpad * 2048;      // rows: [Wq|Wqr|Wkvd|Wkr|pad]
    u16* WkvuT  = p; p += (size_t)4096 * 512;
    u16* WoT    = p; p += (size_t)2048 * 2048;
    u16* proj   = p; p += (size_t)M * NPpad;         // [q_c|q_r|c_kv|k_r] row-major
    u16* kv     = p; p += (size_t)M * 4096;
    u16* v_t    = p; p += (size_t)B * H * 128 * S;
    u16* attn   = p; p += (size_t)M * 2048;

    u16* q_c = proj;                 // cols 0..2047
    u16* q_r = proj + 2048;          // cols 2048..3071
    u16* ckv = proj + 3072;          // cols 3072..3583
    u16* k_r = proj + 3584;          // cols 3584..3647

    // 1) casts / transposes (Wq, Wq_rope pre-scaled by 1/sqrt(192)*log2e)
    cast_f32_bf16<<<(M * D) / 4 / 256, 256, 0, stream>>>(x, xb, M * D);
    transpose_cast<<<dim3(32, 32), 256, 0, stream>>>(Wq,   WprojT,               2048, 2048, scale);
    transpose_cast<<<dim3(32, 16), 256, 0, stream>>>(Wqr,  WprojT + 2048 * 2048, 2048, 1024, scale);
    transpose_cast<<<dim3(32, 8),  256, 0, stream>>>(Wkvd, WprojT + 3072 * 2048, 2048, 512, 1.0f);
    transpose_cast<<<dim3(32, 1),  256, 0, stream>>>(Wkr,  WprojT + 3584 * 2048, 2048, 64, 1.0f);
    transpose_cast<<<dim3(8, 64),  256, 0, stream>>>(Wkvu, WkvuT, 512, 4096, 1.0f);
    transpose_cast<<<dim3(32, 32), 256, 0, stream>>>(Wo,   WoT,   2048, 2048, 1.0f);

    // 2) merged projection GEMM: proj = xb @ WprojT^T  (grid 32x29 = 928 blocks)
    gemm_bt<0, 2048, NP><<<dim3(32, 29), 256, 0, stream>>>(xb, 2048, WprojT, proj, NPpad);

    // 3) RoPE (in place on proj slices; q_r pre-scaled — rotation linear, scale commutes)
    rope_kernel<<<(M * 16 * 32) / 256, 256, 0, stream>>>(q_r, M, 16, S - 1, NPpad);
    rope_kernel<<<(M * 32) / 256, 256, 0, stream>>>(k_r, M, 1, S - 1, NPpad);

    // 4) kv up-projection (A = c_kv inside proj, lda = NPpad), V transpose
    gemm_bt<0, 512, 4096><<<dim3(32, 32), 256, 0, stream>>>(ckv, NPpad, WkvuT, kv, 4096);
    transpose_v<<<dim3(32, 2, 32), 256, 0, stream>>>(kv, v_t, S);

    // 5) attention — grid (bh, 16 q-tiles of 128): pair-balanced, XCD/CU-pinned
    mla_attn<<<dim3(32, 16), 256, 0, stream>>>(q_c, NPpad, q_r, NPpad, kv, k_r, NPpad,
                                               v_t, attn, S);

    // 6) output projection -> fp32 d_out
    gemm_bt<1, 2048, 2048><<<dim3(32, 16), 256, 0, stream>>>(attn, 2048, WoT, d_out, 2048);
}